// Round 9
// baseline (42.844 us; speedup 1.0000x reference)
//
#include <hip/hip_runtime.h>

#define NX 4096
#define NY 2048
#define NQ 1024         // float4 quads per row
#define EPS 1e-8f
#define ROWS 8          // rows per wave strip
#define INV_D 0.001f

typedef float f32x2 __attribute__((ext_vector_type(2)));
typedef float f32x4 __attribute__((ext_vector_type(4)));

__device__ __forceinline__ int clampi(int i, int lo, int hi) {
    return i < lo ? lo : (i > hi ? hi : i);
}

// Packed (2-wide) one-rcp WENO5: two independent faces at once.
__device__ __forceinline__ f32x2 weno5_pk(f32x2 qm2, f32x2 qm1, f32x2 q0,
                                          f32x2 qp1, f32x2 qp2) {
    f32x2 f1 = (1.0f/3.0f)*qm2 - (7.0f/6.0f)*qm1 + (11.0f/6.0f)*q0;
    f32x2 f2 = (-1.0f/6.0f)*qm1 + (5.0f/6.0f)*q0 + (1.0f/3.0f)*qp1;
    f32x2 f3 = (1.0f/3.0f)*q0 + (5.0f/6.0f)*qp1 - (1.0f/6.0f)*qp2;
    f32x2 d1 = qm2 - 2.0f*qm1 + q0;
    f32x2 e1 = qm2 - 4.0f*qm1 + 3.0f*q0;
    f32x2 d2 = qm1 - 2.0f*q0 + qp1;
    f32x2 e2 = qm1 - qp1;
    f32x2 d3 = q0 - 2.0f*qp1 + qp2;
    f32x2 e3 = 3.0f*q0 - 4.0f*qp1 + qp2;
    const float k1 = 13.0f/12.0f, k2 = 0.25f;
    f32x2 b1 = k1*(d1*d1) + k2*(e1*e1);
    f32x2 b2 = k1*(d2*d2) + k2*(e2*e2);
    f32x2 b3 = k1*(d3*d3) + k2*(e3*e3);
    f32x2 t1 = b1 + EPS, t2 = b2 + EPS, t3 = b3 + EPS;
    f32x2 p23 = t2*t3, p13 = t1*t3, p12 = t1*t2;
    f32x2 w1 = 0.1f*(p23*p23);
    f32x2 w2 = 0.6f*(p13*p13);
    f32x2 w3 = 0.3f*(p12*p12);
    f32x2 num = w1*f1 + w2*f2 + w3*f3;
    f32x2 den = (w1 + w2) + w3;
    f32x2 rc;
    rc.x = __builtin_amdgcn_rcpf(den.x);
    rc.y = __builtin_amdgcn_rcpf(den.y);
    return num * rc;
}

// One thread owns a float4-aligned quad of 4 columns for an 8-row strip.
// All h/u/v/out bulk traffic is dwordx4; only the 6-col x-halo + u[c0-1]
// are scalar loads (L1 hits on lines fetched by neighboring lanes).
__global__ __launch_bounds__(256) void adv_kernel(const float* __restrict__ h,
                                                  const float* __restrict__ u,
                                                  const float* __restrict__ v,
                                                  float* __restrict__ out) {
    const int lane = threadIdx.x & 63;
    const int wid  = threadIdx.x >> 6;
    const int q  = blockIdx.x * 64 + lane;      // quad index 0..1023
    const int c0 = q * 4;                        // first column of quad
    const int y0 = (blockIdx.y * 4 + wid) * ROWS;

    const f32x4* __restrict__ h4 = (const f32x4*)h;
    const f32x4* __restrict__ u4 = (const f32x4*)u;
    const f32x4* __restrict__ v4 = (const f32x4*)v;
    f32x4* __restrict__ out4 = (f32x4*)out;

    // clamped x-halo columns (row-invariant; only edge quads actually clamp)
    const int cm3 = clampi(c0 - 3, 0, NX - 1);
    const int cm2 = clampi(c0 - 2, 0, NX - 1);
    const int cm1 = clampi(c0 - 1, 0, NX - 1);
    const int cp4 = clampi(c0 + 4, 0, NX - 1);
    const int cp5 = clampi(c0 + 5, 0, NX - 1);
    const int cp6 = clampi(c0 + 6, 0, NX - 1);

    // ================= batched float4 loads =================
    f32x4 B[ROWS + 6];                  // h rows y0-3 .. y0+10, own quad
#pragma unroll
    for (int k = 0; k < ROWS + 6; ++k)
        B[k] = h4[(size_t)clampi(y0 - 3 + k, 0, NY - 1) * NQ + q];

    f32x4 vv[ROWS + 1];                 // v at face rows y0-1 .. y0+7
#pragma unroll
    for (int j = 0; j <= ROWS; ++j) {
        int fy = y0 - 1 + j; if (fy < 0) fy = 0;
        vv[j] = __builtin_nontemporal_load(&v4[(size_t)fy * NQ + q]);
    }

    f32x4 uu[ROWS];                     // u at cols c0..c0+3 per row
    float um[ROWS];                     // u at col c0-1 per row
#pragma unroll
    for (int r = 0; r < ROWS; ++r) {
        uu[r] = __builtin_nontemporal_load(&u4[(size_t)(y0 + r) * NQ + q]);
        um[r] = u[(size_t)(y0 + r) * NX + cm1];
    }

    // ================= fn faces: 2 pk-weno per face row =================
    f32x4 fn[ROWS + 1];                 // fn[j] = flux at face row y0-1+j
#pragma unroll
    for (int j = 0; j <= ROWS; ++j) {
        bool sx = vv[j].x >= 0.0f, sy = vv[j].y >= 0.0f;
        bool sz = vv[j].z >= 0.0f, sw = vv[j].w >= 0.0f;
        f32x2 a = { sx ? B[j].x   : B[j+5].x, sy ? B[j].y   : B[j+5].y };
        f32x2 b = { sx ? B[j+1].x : B[j+4].x, sy ? B[j+1].y : B[j+4].y };
        f32x2 c = { sx ? B[j+2].x : B[j+3].x, sy ? B[j+2].y : B[j+3].y };
        f32x2 d = { sx ? B[j+3].x : B[j+2].x, sy ? B[j+3].y : B[j+2].y };
        f32x2 e = { sx ? B[j+4].x : B[j+1].x, sy ? B[j+4].y : B[j+1].y };
        f32x2 r1 = weno5_pk(a, b, c, d, e);
        a = { sz ? B[j].z   : B[j+5].z, sw ? B[j].w   : B[j+5].w };
        b = { sz ? B[j+1].z : B[j+4].z, sw ? B[j+1].w : B[j+4].w };
        c = { sz ? B[j+2].z : B[j+3].z, sw ? B[j+2].w : B[j+3].w };
        d = { sz ? B[j+3].z : B[j+2].z, sw ? B[j+3].w : B[j+2].w };
        e = { sz ? B[j+4].z : B[j+1].z, sw ? B[j+4].w : B[j+1].w };
        f32x2 r2 = weno5_pk(a, b, c, d, e);
        fn[j].x = vv[j].x * r1.x;  fn[j].y = vv[j].y * r1.y;
        fn[j].z = vv[j].z * r2.x;  fn[j].w = vv[j].w * r2.y;
    }

    const bool okx = (q > 0);           // cols 4q,4q+1 ghost only at q==0
    const bool okz = (q < NQ - 1);      // cols 4q+2,4q+3 ghost only at q==1023

    // ================= per-row fe faces + combine + store =================
#pragma unroll
    for (int r = 0; r < ROWS; ++r) {
        const int y = y0 + r;
        const float* hr = h + (size_t)y * NX;
        // stencil s0..s9 = h[y][c0-3 .. c0+6]
        float s0 = hr[cm3], s1 = hr[cm2], s2 = hr[cm1];
        float s3 = B[r+3].x, s4 = B[r+3].y, s5 = B[r+3].z, s6 = B[r+3].w;
        float s7 = hr[cp4], s8 = hr[cp5], s9 = hr[cp6];

        float uA = um[r];
        f32x4 uB = uu[r];
        bool tA = uA   >= 0.0f, t0 = uB.x >= 0.0f, t1 = uB.y >= 0.0f,
             t2 = uB.z >= 0.0f, t3 = uB.w >= 0.0f;

        // faces at cols c0-1..c0+3; face t window = s[t+1 .. t+6]
        f32x2 a = { tA ? s0 : s5, t0 ? s1 : s6 };
        f32x2 b = { tA ? s1 : s4, t0 ? s2 : s5 };
        f32x2 c = { tA ? s2 : s3, t0 ? s3 : s4 };
        f32x2 d = { tA ? s3 : s2, t0 ? s4 : s3 };
        f32x2 e = { tA ? s4 : s1, t0 ? s5 : s2 };
        f32x2 qA0 = weno5_pk(a, b, c, d, e);
        a = { t1 ? s2 : s7, t2 ? s3 : s8 };
        b = { t1 ? s3 : s6, t2 ? s4 : s7 };
        c = { t1 ? s4 : s5, t2 ? s5 : s6 };
        d = { t1 ? s5 : s4, t2 ? s6 : s5 };
        e = { t1 ? s6 : s3, t2 ? s7 : s4 };
        f32x2 q12 = weno5_pk(a, b, c, d, e);
        a = { t3 ? s4 : s9, t3 ? s4 : s9 };
        b = { t3 ? s5 : s8, t3 ? s5 : s8 };
        c = { t3 ? s6 : s7, t3 ? s6 : s7 };
        d = { t3 ? s7 : s6, t3 ? s7 : s6 };
        e = { t3 ? s8 : s5, t3 ? s8 : s5 };
        f32x2 q33 = weno5_pk(a, b, c, d, e);

        float fm = uA   * qA0.x;   // face c0-1
        float f0 = uB.x * qA0.y;   // face c0
        float f1 = uB.y * q12.x;   // face c0+1
        float f2 = uB.z * q12.y;   // face c0+2
        float f3 = uB.w * q33.x;   // face c0+3

        const bool rok = (y >= 2) && (y < NY - 2);
        f32x4 val;
        val.x = (rok && okx) ? ((fm - f0) + (fn[r].x - fn[r+1].x)) * INV_D : 0.0f;
        val.y = (rok && okx) ? ((f0 - f1) + (fn[r].y - fn[r+1].y)) * INV_D : 0.0f;
        val.z = (rok && okz) ? ((f1 - f2) + (fn[r].z - fn[r+1].z)) * INV_D : 0.0f;
        val.w = (rok && okz) ? ((f2 - f3) + (fn[r].w - fn[r+1].w)) * INV_D : 0.0f;
        __builtin_nontemporal_store(val, &out4[(size_t)y * NQ + q]);
    }
}

extern "C" void kernel_launch(void* const* d_in, const int* in_sizes, int n_in,
                              void* d_out, int out_size, void* d_ws, size_t ws_size,
                              hipStream_t stream) {
    const float* h = (const float*)d_in[0];
    const float* u = (const float*)d_in[1];
    const float* v = (const float*)d_in[2];
    float* out = (float*)d_out;

    dim3 block(256, 1, 1);
    dim3 grid(NQ / 64, NY / (4 * ROWS), 1);   // 16 x 64
    adv_kernel<<<grid, block, 0, stream>>>(h, u, v, out);
}

// Round 10
// 40.768 us; speedup vs baseline: 1.0509x; 1.0509x over previous
//
#include <hip/hip_runtime.h>

#define NX 4096
#define NY 2048
#define EPS 1e-8f
#define CPW 63          // output columns per block
#define INV_D 0.001f

typedef float f32x2 __attribute__((ext_vector_type(2)));

__device__ __forceinline__ int clampi(int i, int lo, int hi) {
    return i < lo ? lo : (i > hi ? hi : i);
}

// Scalar one-rcp WENO5.
__device__ __forceinline__ float weno5_s(float qm2, float qm1, float q0,
                                         float qp1, float qp2) {
    float f1 = fmaf(1.0f/3.0f, qm2, fmaf(-7.0f/6.0f, qm1, (11.0f/6.0f)*q0));
    float f2 = fmaf(-1.0f/6.0f, qm1, fmaf(5.0f/6.0f, q0, (1.0f/3.0f)*qp1));
    float f3 = fmaf(1.0f/3.0f, q0, fmaf(5.0f/6.0f, qp1, (-1.0f/6.0f)*qp2));
    const float k1 = 13.0f/12.0f, k2 = 0.25f;
    float d1 = qm2 - 2.0f*qm1 + q0,  e1 = qm2 - 4.0f*qm1 + 3.0f*q0;
    float d2 = qm1 - 2.0f*q0 + qp1,  e2 = qm1 - qp1;
    float d3 = q0 - 2.0f*qp1 + qp2,  e3 = 3.0f*q0 - 4.0f*qp1 + qp2;
    float b1 = fmaf(k1, d1*d1, k2*(e1*e1));
    float b2 = fmaf(k1, d2*d2, k2*(e2*e2));
    float b3 = fmaf(k1, d3*d3, k2*(e3*e3));
    float t1 = b1 + EPS, t2 = b2 + EPS, t3 = b3 + EPS;
    float p23 = t2*t3, p13 = t1*t3, p12 = t1*t2;
    float w1 = 0.1f*(p23*p23), w2 = 0.6f*(p13*p13), w3 = 0.3f*(p12*p12);
    float num = fmaf(w1, f1, fmaf(w2, f2, w3*f3));
    return num * __builtin_amdgcn_rcpf((w1 + w2) + w3);
}

// Packed (2-wide) one-rcp WENO5: two independent faces at once.
__device__ __forceinline__ f32x2 weno5_pk(f32x2 qm2, f32x2 qm1, f32x2 q0,
                                          f32x2 qp1, f32x2 qp2) {
    f32x2 f1 = (1.0f/3.0f)*qm2 - (7.0f/6.0f)*qm1 + (11.0f/6.0f)*q0;
    f32x2 f2 = (-1.0f/6.0f)*qm1 + (5.0f/6.0f)*q0 + (1.0f/3.0f)*qp1;
    f32x2 f3 = (1.0f/3.0f)*q0 + (5.0f/6.0f)*qp1 - (1.0f/6.0f)*qp2;
    f32x2 d1 = qm2 - 2.0f*qm1 + q0;
    f32x2 e1 = qm2 - 4.0f*qm1 + 3.0f*q0;
    f32x2 d2 = qm1 - 2.0f*q0 + qp1;
    f32x2 e2 = qm1 - qp1;
    f32x2 d3 = q0 - 2.0f*qp1 + qp2;
    f32x2 e3 = 3.0f*q0 - 4.0f*qp1 + qp2;
    const float k1 = 13.0f/12.0f, k2 = 0.25f;
    f32x2 b1 = k1*(d1*d1) + k2*(e1*e1);
    f32x2 b2 = k1*(d2*d2) + k2*(e2*e2);
    f32x2 b3 = k1*(d3*d3) + k2*(e3*e3);
    f32x2 t1 = b1 + EPS, t2 = b2 + EPS, t3 = b3 + EPS;
    f32x2 p23 = t2*t3, p13 = t1*t3, p12 = t1*t2;
    f32x2 w1 = 0.1f*(p23*p23);
    f32x2 w2 = 0.6f*(p13*p13);
    f32x2 w3 = 0.3f*(p12*p12);
    f32x2 num = w1*f1 + w2*f2 + w3*f3;
    f32x2 den = (w1 + w2) + w3;
    f32x2 rc;
    rc.x = __builtin_amdgcn_rcpf(den.x);
    rc.y = __builtin_amdgcn_rcpf(den.y);
    return num * rc;
}

// One thread: 2 rows x 1 column. 23 loads in one short batch, then
// 2 packed + 1 scalar WENO. Minimal per-wave dependency chain; 67k waves.
template <bool EDGE>
__device__ __forceinline__ void run_strip(const float* __restrict__ h,
                                          const float* __restrict__ u,
                                          const float* __restrict__ v,
                                          float* __restrict__ out,
                                          int x0, int y0w, int lane) {
    const int xf = x0 - 1 + lane;                       // x-face this lane owns
    const int xo = x0 + lane;                           // output column
    const int xc = EDGE ? (xo < NX ? xo : NX - 1) : xo;
    const int xq = EDGE ? clampi(xf, 0, NX - 1) : xf;

    int xs[6];
    if (EDGE) {
#pragma unroll
        for (int k = 0; k < 6; ++k) xs[k] = clampi(xf - 2 + k, 0, NX - 1);
    }

    // ---- 23 loads (one batch; chain depth 1) ----
    // column xc, rows y0w-3..-1 and y0w+2..+4 (rows y0w,y0w+1 come from st)
    float C0, C1, C2, C5, C6, C7;
    if (EDGE) {
        C0 = h[(size_t)clampi(y0w - 3, 0, NY - 1) * NX + xc];
        C1 = h[(size_t)clampi(y0w - 2, 0, NY - 1) * NX + xc];
        C2 = h[(size_t)clampi(y0w - 1, 0, NY - 1) * NX + xc];
        C5 = h[(size_t)clampi(y0w + 2, 0, NY - 1) * NX + xc];
        C6 = h[(size_t)clampi(y0w + 3, 0, NY - 1) * NX + xc];
        C7 = h[(size_t)clampi(y0w + 4, 0, NY - 1) * NX + xc];
    } else {
        const float* hc = h + (size_t)y0w * NX + xc;
        C0 = hc[-3 * NX]; C1 = hc[-2 * NX]; C2 = hc[-NX];
        C5 = hc[2 * NX];  C6 = hc[3 * NX];  C7 = hc[4 * NX];
    }
    float st0[6], st1[6];
    {
        const float* hr0 = h + (size_t)y0w * NX;
        const float* hr1 = hr0 + NX;
        if (EDGE) {
#pragma unroll
            for (int k = 0; k < 6; ++k) { st0[k] = hr0[xs[k]]; st1[k] = hr1[xs[k]]; }
        } else {
#pragma unroll
            for (int k = 0; k < 6; ++k) { st0[k] = hr0[xf - 2 + k]; st1[k] = hr1[xf - 2 + k]; }
        }
    }
    float u0 = u[(size_t)y0w * NX + xq];
    float u1 = u[(size_t)(y0w + 1) * NX + xq];
    float va, vb, vcv;
    {
        int fy = EDGE ? clampi(y0w - 1, 0, NY - 1) : (y0w - 1);
        va  = v[(size_t)fy * NX + xc];
        vb  = v[(size_t)y0w * NX + xc];
        vcv = v[(size_t)(y0w + 1) * NX + xc];
    }

    const float C3 = st0[3];   // h[y0w][xc]
    const float C4 = st1[3];   // h[y0w+1][xc]

    // ---- fn faces at rows y0w-1, y0w (packed) and y0w+1 (scalar) ----
    bool p0 = (va >= 0.0f), p1 = (vb >= 0.0f), p2 = (vcv >= 0.0f);
    f32x2 a = { p0 ? C0 : C5, p1 ? C1 : C6 };
    f32x2 b = { p0 ? C1 : C4, p1 ? C2 : C5 };
    f32x2 c = { p0 ? C2 : C3, p1 ? C3 : C4 };
    f32x2 d = { p0 ? C3 : C2, p1 ? C4 : C3 };
    f32x2 e = { p0 ? C4 : C1, p1 ? C5 : C2 };
    f32x2 qn = weno5_pk(a, b, c, d, e);
    float f0 = va * qn.x;
    float f1 = vb * qn.y;
    float f2 = vcv * weno5_s(p2 ? C2 : C7, p2 ? C3 : C6, p2 ? C4 : C5,
                             p2 ? C5 : C4, p2 ? C6 : C3);

    // ---- fe faces for both rows (packed) ----
    bool t0 = (u0 >= 0.0f), t1 = (u1 >= 0.0f);
    a = { t0 ? st0[0] : st0[5], t1 ? st1[0] : st1[5] };
    b = { t0 ? st0[1] : st0[4], t1 ? st1[1] : st1[4] };
    c = { t0 ? st0[2] : st0[3], t1 ? st1[2] : st1[3] };
    d = { t0 ? st0[3] : st0[2], t1 ? st1[3] : st1[2] };
    e = { t0 ? st0[4] : st0[1], t1 ? st1[4] : st1[1] };
    f32x2 qe = weno5_pk(a, b, c, d, e);
    float fe0 = u0 * qe.x;
    float fe1 = u1 * qe.y;
    float fe0r = __shfl_down(fe0, 1);
    float fe1r = __shfl_down(fe1, 1);

    float val0 = ((fe0 - fe0r) + (f0 - f1)) * INV_D;
    float val1 = ((fe1 - fe1r) + (f1 - f2)) * INV_D;

    if (EDGE) {
        if (xo < 2 || xo >= NX - 2 || y0w < 2 || y0w >= NY - 2) val0 = 0.0f;
        if (xo < 2 || xo >= NX - 2 || y0w + 1 < 2 || y0w + 1 >= NY - 2) val1 = 0.0f;
        if (lane < CPW && xo < NX) {
            __builtin_nontemporal_store(val0, out + (size_t)y0w * NX + xo);
            __builtin_nontemporal_store(val1, out + (size_t)(y0w + 1) * NX + xo);
        }
    } else {
        if (lane < CPW) {
            __builtin_nontemporal_store(val0, out + (size_t)y0w * NX + xo);
            __builtin_nontemporal_store(val1, out + (size_t)(y0w + 1) * NX + xo);
        }
    }
}

__global__ __launch_bounds__(256) void adv_kernel(const float* __restrict__ h,
                                                  const float* __restrict__ u,
                                                  const float* __restrict__ v,
                                                  float* __restrict__ out) {
    const int lane = threadIdx.x & 63;
    const int wid  = threadIdx.x >> 6;
    const int x0 = blockIdx.x * CPW;
    const int y0w = blockIdx.y * 8 + wid * 2;   // 2 rows per wave

    const bool edge = (blockIdx.x == 0) || (blockIdx.x >= 64) ||
                      (blockIdx.y == 0) || (blockIdx.y == gridDim.y - 1);
    if (edge)
        run_strip<true>(h, u, v, out, x0, y0w, lane);
    else
        run_strip<false>(h, u, v, out, x0, y0w, lane);
}

extern "C" void kernel_launch(void* const* d_in, const int* in_sizes, int n_in,
                              void* d_out, int out_size, void* d_ws, size_t ws_size,
                              hipStream_t stream) {
    const float* h = (const float*)d_in[0];
    const float* u = (const float*)d_in[1];
    const float* v = (const float*)d_in[2];
    float* out = (float*)d_out;

    dim3 block(256, 1, 1);
    dim3 grid((NX + CPW - 1) / CPW, NY / 8, 1);   // 66 x 256
    adv_kernel<<<grid, block, 0, stream>>>(h, u, v, out);
}

// Round 11
// 39.993 us; speedup vs baseline: 1.0713x; 1.0194x over previous
//
#include <hip/hip_runtime.h>

#define NX 4096
#define NY 2048
#define EPS 1e-8f
#define CPW 63          // output columns per block
#define INV_D 0.001f

typedef float f32x2 __attribute__((ext_vector_type(2)));

__device__ __forceinline__ int clampi(int i, int lo, int hi) {
    return i < lo ? lo : (i > hi ? hi : i);
}

// Scalar one-rcp WENO5 (block-bottom fn face, wave 0 only).
__device__ __forceinline__ float weno5_s(float qm2, float qm1, float q0,
                                         float qp1, float qp2) {
    float f1 = fmaf(1.0f/3.0f, qm2, fmaf(-7.0f/6.0f, qm1, (11.0f/6.0f)*q0));
    float f2 = fmaf(-1.0f/6.0f, qm1, fmaf(5.0f/6.0f, q0, (1.0f/3.0f)*qp1));
    float f3 = fmaf(1.0f/3.0f, q0, fmaf(5.0f/6.0f, qp1, (-1.0f/6.0f)*qp2));
    const float k1 = 13.0f/12.0f, k2 = 0.25f;
    float d1 = qm2 - 2.0f*qm1 + q0,  e1 = qm2 - 4.0f*qm1 + 3.0f*q0;
    float d2 = qm1 - 2.0f*q0 + qp1,  e2 = qm1 - qp1;
    float d3 = q0 - 2.0f*qp1 + qp2,  e3 = 3.0f*q0 - 4.0f*qp1 + qp2;
    float b1 = fmaf(k1, d1*d1, k2*(e1*e1));
    float b2 = fmaf(k1, d2*d2, k2*(e2*e2));
    float b3 = fmaf(k1, d3*d3, k2*(e3*e3));
    float t1 = b1 + EPS, t2 = b2 + EPS, t3 = b3 + EPS;
    float p23 = t2*t3, p13 = t1*t3, p12 = t1*t2;
    float w1 = 0.1f*(p23*p23), w2 = 0.6f*(p13*p13), w3 = 0.3f*(p12*p12);
    float num = fmaf(w1, f1, fmaf(w2, f2, w3*f3));
    return num * __builtin_amdgcn_rcpf((w1 + w2) + w3);
}

// Packed (2-wide) one-rcp WENO5: two independent faces at once.
__device__ __forceinline__ f32x2 weno5_pk(f32x2 qm2, f32x2 qm1, f32x2 q0,
                                          f32x2 qp1, f32x2 qp2) {
    f32x2 f1 = (1.0f/3.0f)*qm2 - (7.0f/6.0f)*qm1 + (11.0f/6.0f)*q0;
    f32x2 f2 = (-1.0f/6.0f)*qm1 + (5.0f/6.0f)*q0 + (1.0f/3.0f)*qp1;
    f32x2 f3 = (1.0f/3.0f)*q0 + (5.0f/6.0f)*qp1 - (1.0f/6.0f)*qp2;
    f32x2 d1 = qm2 - 2.0f*qm1 + q0;
    f32x2 e1 = qm2 - 4.0f*qm1 + 3.0f*q0;
    f32x2 d2 = qm1 - 2.0f*q0 + qp1;
    f32x2 e2 = qm1 - qp1;
    f32x2 d3 = q0 - 2.0f*qp1 + qp2;
    f32x2 e3 = 3.0f*q0 - 4.0f*qp1 + qp2;
    const float k1 = 13.0f/12.0f, k2 = 0.25f;
    f32x2 b1 = k1*(d1*d1) + k2*(e1*e1);
    f32x2 b2 = k1*(d2*d2) + k2*(e2*e2);
    f32x2 b3 = k1*(d3*d3) + k2*(e3*e3);
    f32x2 t1 = b1 + EPS, t2 = b2 + EPS, t3 = b3 + EPS;
    f32x2 p23 = t2*t3, p13 = t1*t3, p12 = t1*t2;
    f32x2 w1 = 0.1f*(p23*p23);
    f32x2 w2 = 0.6f*(p13*p13);
    f32x2 w3 = 0.3f*(p12*p12);
    f32x2 num = w1*f1 + w2*f2 + w3*f3;
    f32x2 den = (w1 + w2) + w3;
    f32x2 rc;
    rc.x = __builtin_amdgcn_rcpf(den.x);
    rc.y = __builtin_amdgcn_rcpf(den.y);
    return num * rc;
}

// One thread: 2 rows x 1 column. Each wave computes ONLY its 2 fn faces
// (1 pk-WENO); the face below comes from the adjacent wave via LDS (wave 0
// computes it scalar). fe pk-WENO sits between LDS-write and barrier to
// hide sync skew. ~1.03 WENO streams/cell (vs 1.5 in the unshared version).
template <bool EDGE>
__device__ __forceinline__ void run_strip(const float* __restrict__ h,
                                          const float* __restrict__ u,
                                          const float* __restrict__ v,
                                          float* __restrict__ out,
                                          float (*fsh)[64],
                                          int x0, int yA, int lane, int wid) {
    const int yB = yA + 1;
    const int xf = x0 - 1 + lane;                       // x-face this lane owns
    const int xo = x0 + lane;                           // output column
    const int xc = EDGE ? (xo < NX ? xo : NX - 1) : xo;
    const int xq = EDGE ? clampi(xf, 0, NX - 1) : xf;

    int xs[6];
    if (EDGE) {
#pragma unroll
        for (int k = 0; k < 6; ++k) xs[k] = clampi(xf - 2 + k, 0, NX - 1);
    }

    // ---- loads (short batch, chain depth 1) ----
    float Cm2, Cm1, Cp2, Cp3, Cp4;      // h col xc at rows yA-2,-1,+2,+3,+4
    if (EDGE) {
        Cm2 = h[(size_t)clampi(yA - 2, 0, NY - 1) * NX + xc];
        Cm1 = h[(size_t)clampi(yA - 1, 0, NY - 1) * NX + xc];
        Cp2 = h[(size_t)clampi(yA + 2, 0, NY - 1) * NX + xc];
        Cp3 = h[(size_t)clampi(yA + 3, 0, NY - 1) * NX + xc];
        Cp4 = h[(size_t)clampi(yA + 4, 0, NY - 1) * NX + xc];
    } else {
        const float* hc = h + (size_t)yA * NX + xc;
        Cm2 = hc[-2 * NX]; Cm1 = hc[-NX];
        Cp2 = hc[2 * NX];  Cp3 = hc[3 * NX]; Cp4 = hc[4 * NX];
    }
    float Cm3 = 0.0f, vm = 0.0f;        // wave 0 only (block-bottom face)
    if (wid == 0) {
        if (EDGE) {
            Cm3 = h[(size_t)clampi(yA - 3, 0, NY - 1) * NX + xc];
            vm  = v[(size_t)clampi(yA - 1, 0, NY - 1) * NX + xc];
        } else {
            Cm3 = h[(size_t)(yA - 3) * NX + xc];
            vm  = v[(size_t)(yA - 1) * NX + xc];
        }
    }
    float st0[6], st1[6];
    {
        const float* hr0 = h + (size_t)yA * NX;
        const float* hr1 = hr0 + NX;
        if (EDGE) {
#pragma unroll
            for (int k = 0; k < 6; ++k) { st0[k] = hr0[xs[k]]; st1[k] = hr1[xs[k]]; }
        } else {
#pragma unroll
            for (int k = 0; k < 6; ++k) { st0[k] = hr0[xf - 2 + k]; st1[k] = hr1[xf - 2 + k]; }
        }
    }
    float u0 = u[(size_t)yA * NX + xq];
    float u1 = u[(size_t)yB * NX + xq];
    float vA = v[(size_t)yA * NX + xc];
    float vB = v[(size_t)yB * NX + xc];

    const float CA = st0[3];   // h[yA][xc]
    const float CB = st1[3];   // h[yB][xc]

    // ---- fn faces yA, yB (one packed WENO) ----
    bool pA = (vA >= 0.0f), pB = (vB >= 0.0f);
    f32x2 a = { pA ? Cm2 : Cp3, pB ? Cm1 : Cp4 };
    f32x2 b = { pA ? Cm1 : Cp2, pB ? CA  : Cp3 };
    f32x2 c = { pA ? CA  : CB,  pB ? CB  : Cp2 };
    f32x2 d = { pA ? CB  : CA,  pB ? Cp2 : CB  };
    f32x2 e = { pA ? Cp2 : Cm1, pB ? Cp3 : CA  };
    f32x2 qn = weno5_pk(a, b, c, d, e);
    float fnA = vA * qn.x;     // face (yA, yA+1)... face index yA
    float fnB = vB * qn.y;     // face index yB

    // block-bottom face (index yA-1), wave 0 only
    float fn_m1 = 0.0f;
    if (wid == 0) {
        bool pm = (vm >= 0.0f);
        fn_m1 = vm * weno5_s(pm ? Cm3 : Cp2, pm ? Cm2 : CB, pm ? Cm1 : CA,
                             pm ? CA : Cm1,  pm ? CB : Cm2);
    }
    if (wid < 3) fsh[wid][lane] = fnB;   // wave w+1 reads this as its face yA-1

    // ---- fe faces for both rows (packed) — independent of the barrier ----
    bool t0 = (u0 >= 0.0f), t1 = (u1 >= 0.0f);
    a = { t0 ? st0[0] : st0[5], t1 ? st1[0] : st1[5] };
    b = { t0 ? st0[1] : st0[4], t1 ? st1[1] : st1[4] };
    c = { t0 ? st0[2] : st0[3], t1 ? st1[2] : st1[3] };
    d = { t0 ? st0[3] : st0[2], t1 ? st1[3] : st1[2] };
    e = { t0 ? st0[4] : st0[1], t1 ? st1[4] : st1[1] };
    f32x2 qe = weno5_pk(a, b, c, d, e);
    float fe0 = u0 * qe.x;
    float fe1 = u1 * qe.y;
    float fe0r = __shfl_down(fe0, 1);
    float fe1r = __shfl_down(fe1, 1);

    __syncthreads();
    float fn_below = (wid == 0) ? fn_m1 : fsh[wid - 1][lane];

    float val0 = ((fe0 - fe0r) + (fn_below - fnA)) * INV_D;
    float val1 = ((fe1 - fe1r) + (fnA - fnB)) * INV_D;

    if (EDGE) {
        if (xo < 2 || xo >= NX - 2 || yA < 2 || yA >= NY - 2) val0 = 0.0f;
        if (xo < 2 || xo >= NX - 2 || yB < 2 || yB >= NY - 2) val1 = 0.0f;
        if (lane < CPW && xo < NX) {
            __builtin_nontemporal_store(val0, out + (size_t)yA * NX + xo);
            __builtin_nontemporal_store(val1, out + (size_t)yB * NX + xo);
        }
    } else {
        if (lane < CPW) {
            __builtin_nontemporal_store(val0, out + (size_t)yA * NX + xo);
            __builtin_nontemporal_store(val1, out + (size_t)yB * NX + xo);
        }
    }
}

__global__ __launch_bounds__(256) void adv_kernel(const float* __restrict__ h,
                                                  const float* __restrict__ u,
                                                  const float* __restrict__ v,
                                                  float* __restrict__ out) {
    __shared__ float fsh[3][64];
    const int lane = threadIdx.x & 63;
    const int wid  = threadIdx.x >> 6;
    const int x0 = blockIdx.x * CPW;
    const int yA = blockIdx.y * 8 + wid * 2;    // 2 rows per wave

    const bool edge = (blockIdx.x == 0) || (blockIdx.x >= 64) ||
                      (blockIdx.y == 0) || (blockIdx.y == gridDim.y - 1);
    if (edge)
        run_strip<true>(h, u, v, out, fsh, x0, yA, lane, wid);
    else
        run_strip<false>(h, u, v, out, fsh, x0, yA, lane, wid);
}

extern "C" void kernel_launch(void* const* d_in, const int* in_sizes, int n_in,
                              void* d_out, int out_size, void* d_ws, size_t ws_size,
                              hipStream_t stream) {
    const float* h = (const float*)d_in[0];
    const float* u = (const float*)d_in[1];
    const float* v = (const float*)d_in[2];
    float* out = (float*)d_out;

    dim3 block(256, 1, 1);
    dim3 grid((NX + CPW - 1) / CPW, NY / 8, 1);   // 66 x 256
    adv_kernel<<<grid, block, 0, stream>>>(h, u, v, out);
}